// Round 1
// baseline (365.998 us; speedup 1.0000x reference)
//
#include <hip/hip_runtime.h>
#include <hip/hip_bf16.h>

typedef __attribute__((ext_vector_type(8))) short short8;
typedef __attribute__((ext_vector_type(4))) float f32x4;
typedef unsigned short u16;
typedef unsigned int u32;

__device__ __forceinline__ void gload_lds16(const void* g, void* l) {
  typedef const __attribute__((address_space(1))) u32 gu32;
  typedef __attribute__((address_space(3))) u32 lu32;
  __builtin_amdgcn_global_load_lds((gu32*)g, (lu32*)l, 16, 0, 0);
}

__device__ __forceinline__ u16 f2bf(float f) {
  union { float f; u32 u; } v; v.f = f;
  u32 u = v.u + 0x7FFFu + ((v.u >> 16) & 1u);
  return (u16)(u >> 16);
}

__device__ __forceinline__ short8 lds_read8(const u16* base, int byteoff) {
  return *(const short8*)((const char*)base + byteoff);
}

// ---------------- fused fp32 -> bf16 cast of x + 4 weights ----------------
__global__ __launch_bounds__(256) void cast_all_kernel(
    const float* __restrict__ x, const float* __restrict__ wv,
    const float* __restrict__ wu, const float* __restrict__ wov,
    const float* __restrict__ wou, u16* __restrict__ dst) {
  const long N0 = 8388608, N1 = N0 + 262144, N2 = N1 + 786432,
             N3 = N2 + 262144, N4 = N3 + 262144;
  long i = (long)(blockIdx.x * 256 + threadIdx.x) * 8;
  if (i >= N4) return;
  const float* s;
  if (i < N0) s = x + i;
  else if (i < N1) s = wv + (i - N0);
  else if (i < N2) s = wu + (i - N1);
  else if (i < N3) s = wov + (i - N2);
  else s = wou + (i - N3);
  float4 a = *(const float4*)s;
  float4 b = *(const float4*)(s + 4);
  short8 o;
  o[0] = (short)f2bf(a.x); o[1] = (short)f2bf(a.y);
  o[2] = (short)f2bf(a.z); o[3] = (short)f2bf(a.w);
  o[4] = (short)f2bf(b.x); o[5] = (short)f2bf(b.y);
  o[6] = (short)f2bf(b.z); o[7] = (short)f2bf(b.w);
  *(short8*)(dst + i) = o;
}

// ---------------- C[M,N] = A[M,K] * B[N,K]^T, bf16 in, OutT out ----------------
// 4 waves as 2x2; BK=64; XOR slot swizzle (slot ^ row&7) -> ~2-way ds_read conflicts.
template<int BM, int BN, int MR, int NR, typename OutT>
__global__ __launch_bounds__(256) void gemm_bt(
    OutT* __restrict__ C, const u16* __restrict__ A, const u16* __restrict__ B,
    int N, int K) {
  __shared__ u16 As[BM * 64];
  __shared__ u16 Bs[BN * 64];
  const int tid = threadIdx.x;
  const int l = tid & 63, w = tid >> 6;
  const int wr = w >> 1, wc = w & 1;
  const int bm = blockIdx.x * BM, bn = blockIdx.y * BN;
  const int srow = l >> 3, sslot = (l & 7) ^ srow;

  f32x4 acc[MR][NR] = {};

  const u16* Ag = A + (long)(bm + srow) * K + sslot * 8;
  const u16* Bg = B + (long)(bn + srow) * K + sslot * 8;
  constexpr int CA = BM / 32, CB = BN / 32;

  for (int kt = 0; kt < K; kt += 64) {
#pragma unroll
    for (int c = 0; c < CA; ++c) {
      int ch = w * CA + c;
      gload_lds16(Ag + (long)ch * 8 * K + kt, (char*)As + ch * 1024);
    }
#pragma unroll
    for (int c = 0; c < CB; ++c) {
      int ch = w * CB + c;
      gload_lds16(Bg + (long)ch * 8 * K + kt, (char*)Bs + ch * 1024);
    }
    __syncthreads();
    short8 af[MR][2], bf[NR][2];
#pragma unroll
    for (int i = 0; i < MR; ++i)
#pragma unroll
      for (int kk = 0; kk < 2; ++kk) {
        int row = wr * (MR * 16) + i * 16 + (l & 15);
        af[i][kk] = lds_read8(As, row * 128 + (((kk * 4 + (l >> 4)) ^ (l & 7)) * 16));
      }
#pragma unroll
    for (int j = 0; j < NR; ++j)
#pragma unroll
      for (int kk = 0; kk < 2; ++kk) {
        int col = wc * (NR * 16) + j * 16 + (l & 15);
        bf[j][kk] = lds_read8(Bs, col * 128 + (((kk * 4 + (l >> 4)) ^ (l & 7)) * 16));
      }
#pragma unroll
    for (int kk = 0; kk < 2; ++kk)
#pragma unroll
      for (int i = 0; i < MR; ++i)
#pragma unroll
        for (int j = 0; j < NR; ++j)
          acc[i][j] = __builtin_amdgcn_mfma_f32_16x16x32_bf16(
              af[i][kk], bf[j][kk], acc[i][j], 0, 0, 0);
    __syncthreads();
  }
#pragma unroll
  for (int i = 0; i < MR; ++i)
#pragma unroll
    for (int j = 0; j < NR; ++j) {
      int row = bm + wr * (MR * 16) + i * 16 + (l >> 4) * 4;
      int col = bn + wc * (NR * 16) + j * 16 + (l & 15);
#pragma unroll
      for (int r = 0; r < 4; ++r) {
        if constexpr (sizeof(OutT) == 4) {
          C[(long)(row + r) * N + col] = acc[i][j][r];
        } else {
          ((u16*)C)[(long)(row + r) * N + col] = f2bf(acc[i][j][r]);
        }
      }
    }
}

// ---------------- flash attention: 16 heads, D=64, T=2048, non-causal ----------------
// grid (T/128, B*H); 4 waves, each owns 32 q-rows. KBLK=64.
__global__ __launch_bounds__(256) void attn_kernel(
    u16* __restrict__ Y, const u16* __restrict__ QKV) {
  constexpr int T = 2048, LDQ = 3072;
  __shared__ u16 Ks[64 * 64];       // [k][d], slot-swizzled
  __shared__ u16 Vs[64 * 64];       // transposed [d][k], slot-swizzled
  __shared__ u16 Ps[4 * 32 * 64];   // per-wave [q][k], slot-swizzled
  const int tid = threadIdx.x, l = tid & 63, w = tid >> 6;
  const int qt = blockIdx.x, bh = blockIdx.y;
  const int b = bh >> 4, h = bh & 15;
  const long base = (long)b * T * LDQ;
  const int q0 = qt * 128 + w * 32;

  // Q fragments in registers (A-operand): rows q0+i*16+(l&15), k = kk*32+(l>>4)*8
  short8 qf[2][2];
#pragma unroll
  for (int i = 0; i < 2; ++i)
#pragma unroll
    for (int kk = 0; kk < 2; ++kk)
      qf[i][kk] = *(const short8*)(QKV + base +
          (long)(q0 + i * 16 + (l & 15)) * LDQ + h * 64 + kk * 32 + (l >> 4) * 8);

  f32x4 yacc[2][4] = {};
  float mrow[2][4], lrow[2][4];
#pragma unroll
  for (int i = 0; i < 2; ++i)
#pragma unroll
    for (int r = 0; r < 4; ++r) { mrow[i][r] = -3.0e38f; lrow[i][r] = 0.0f; }

  const int srow = l >> 3, sslot = (l & 7) ^ srow;
  const u16* Kg = QKV + base + 1024 + h * 64 + (long)srow * LDQ + sslot * 8;
  const u16* Vg = QKV + base + 2048 + h * 64;

  for (int kt = 0; kt < T; kt += 64) {
    // stage K tile via global_load_lds (pre-swizzled source, linear LDS dest)
#pragma unroll
    for (int c = 0; c < 2; ++c) {
      int ch = w * 2 + c;
      gload_lds16(Kg + (long)(kt + ch * 8) * LDQ, (char*)Ks + ch * 1024);
    }
    // stage V transposed via registers (coalesced 16B loads, scalar LDS writes)
#pragma unroll
    for (int ci = 0; ci < 2; ++ci) {
      int c = tid + ci * 256;
      int vr = c >> 3, d0 = (c & 7) * 8;
      short8 vv = *(const short8*)(Vg + (long)(kt + vr) * LDQ + d0);
#pragma unroll
      for (int jj = 0; jj < 8; ++jj) {
        int d = d0 + jj;
        int byte = d * 128 + (((vr >> 3) ^ (d & 7)) * 16) + (vr & 7) * 2;
        *(u16*)((char*)Vs + byte) = (u16)(short)vv[jj];
      }
    }
    __syncthreads();

    // QK^T
    short8 kf[4][2];
#pragma unroll
    for (int jf = 0; jf < 4; ++jf)
#pragma unroll
      for (int kk = 0; kk < 2; ++kk) {
        int row = jf * 16 + (l & 15);
        kf[jf][kk] = lds_read8(Ks, row * 128 + (((kk * 4 + (l >> 4)) ^ (l & 7)) * 16));
      }
    f32x4 s[2][4] = {};
#pragma unroll
    for (int kk = 0; kk < 2; ++kk)
#pragma unroll
      for (int i = 0; i < 2; ++i)
#pragma unroll
        for (int jf = 0; jf < 4; ++jf)
          s[i][jf] = __builtin_amdgcn_mfma_f32_16x16x32_bf16(
              qf[i][kk], kf[jf][kk], s[i][jf], 0, 0, 0);

    // online softmax in log2 domain: fold scale (1/8) * log2(e)
    constexpr float SC = 0.18033688011112042f;
#pragma unroll
    for (int i = 0; i < 2; ++i) {
#pragma unroll
      for (int jf = 0; jf < 4; ++jf) s[i][jf] *= SC;
#pragma unroll
      for (int r = 0; r < 4; ++r) {
        float tm = fmaxf(fmaxf(s[i][0][r], s[i][1][r]), fmaxf(s[i][2][r], s[i][3][r]));
        tm = fmaxf(tm, __shfl_xor(tm, 1));
        tm = fmaxf(tm, __shfl_xor(tm, 2));
        tm = fmaxf(tm, __shfl_xor(tm, 4));
        tm = fmaxf(tm, __shfl_xor(tm, 8));
        float mn = fmaxf(mrow[i][r], tm);
        float cr = exp2f(mrow[i][r] - mn);
        mrow[i][r] = mn;
        lrow[i][r] *= cr;
#pragma unroll
        for (int n = 0; n < 4; ++n) yacc[i][n][r] *= cr;
        float ps = 0.0f;
#pragma unroll
        for (int jf = 0; jf < 4; ++jf) {
          float p = exp2f(s[i][jf][r] - mn);
          s[i][jf][r] = p;
          ps += p;
        }
        ps += __shfl_xor(ps, 1);
        ps += __shfl_xor(ps, 2);
        ps += __shfl_xor(ps, 4);
        ps += __shfl_xor(ps, 8);
        lrow[i][r] += ps;
      }
      // write P (bf16) to this wave's LDS region (same swizzle scheme)
#pragma unroll
      for (int jf = 0; jf < 4; ++jf)
#pragma unroll
        for (int r = 0; r < 4; ++r) {
          int q = i * 16 + (l >> 4) * 4 + r;
          int k = jf * 16 + (l & 15);
          int byte = w * 4096 + q * 128 + (((k >> 3) ^ (q & 7)) * 16) + (k & 7) * 2;
          *(u16*)((char*)Ps + byte) = f2bf(s[i][jf][r]);
        }
    }

    // PV (per-wave P region: same-wave LDS RAW, compiler inserts lgkmcnt)
    short8 pf[2][2], vf[4][2];
#pragma unroll
    for (int i = 0; i < 2; ++i)
#pragma unroll
      for (int kk = 0; kk < 2; ++kk) {
        int q = i * 16 + (l & 15);
        pf[i][kk] = lds_read8(Ps, w * 4096 + q * 128 + (((kk * 4 + (l >> 4)) ^ (l & 7)) * 16));
      }
#pragma unroll
    for (int n = 0; n < 4; ++n)
#pragma unroll
      for (int kk = 0; kk < 2; ++kk) {
        int d = n * 16 + (l & 15);
        vf[n][kk] = lds_read8(Vs, d * 128 + (((kk * 4 + (l >> 4)) ^ (l & 7)) * 16));
      }
#pragma unroll
    for (int kk = 0; kk < 2; ++kk)
#pragma unroll
      for (int i = 0; i < 2; ++i)
#pragma unroll
        for (int n = 0; n < 4; ++n)
          yacc[i][n] = __builtin_amdgcn_mfma_f32_16x16x32_bf16(
              pf[i][kk], vf[n][kk], yacc[i][n], 0, 0, 0);
    __syncthreads();
  }

  // epilogue: divide by softmax denom, store bf16 [B*T, 1024]
#pragma unroll
  for (int i = 0; i < 2; ++i)
#pragma unroll
    for (int n = 0; n < 4; ++n)
#pragma unroll
      for (int r = 0; r < 4; ++r) {
        int row = b * T + q0 + i * 16 + (l >> 4) * 4 + r;
        int col = h * 64 + n * 16 + (l & 15);
        Y[(long)row * 1024 + col] = f2bf(yacc[i][n][r] / lrow[i][r]);
      }
}

__global__ void ws_too_small_kernel(float* out) { out[0] = 3.0e38f; }

// ---------------- launch ----------------
extern "C" void kernel_launch(void* const* d_in, const int* in_sizes, int n_in,
                              void* d_out, int out_size, void* d_ws, size_t ws_size,
                              hipStream_t stream) {
  (void)in_sizes; (void)n_in; (void)out_size;
  const float* x   = (const float*)d_in[0];
  const float* wv  = (const float*)d_in[1];
  const float* wu  = (const float*)d_in[2];
  const float* wov = (const float*)d_in[3];
  const float* wou = (const float*)d_in[4];
  float* out = (float*)d_out;
  u16* ws = (u16*)d_ws;

  // bf16 workspace layout (element offsets)
  u16* xb   = ws;                // x        [8192,1024]
  u16* wvb  = ws + 8388608;      // W_qkv_v  [256,1024]
  u16* wub  = ws + 8650752;      // W_qkv_u  [3072,256]
  u16* wovb = ws + 9437184;      // W_o_v    [256,1024]
  u16* woub = ws + 9699328;      // W_o_u    [1024,256]
  u16* t    = ws + 9961472;      // x@Wv^T   [8192,256]
  u16* qkv  = ws + 12058624;     // [8192,3072]
  u16* yb   = ws + 37224448;     // attn out [8192,1024]
  u16* z    = ws + 45613056;     // y@Wov^T  [8192,256]
  // total 47,710,208 bf16 elements = 95,420,416 bytes

  if (ws_size < 95420416ull) {   // distinctive failure marker
    ws_too_small_kernel<<<1, 1, 0, stream>>>(out);
    return;
  }

  cast_all_kernel<<<dim3(4864), dim3(256), 0, stream>>>(x, wv, wu, wov, wou, ws);
  // t = x @ Wv^T           M=8192 N=256  K=1024
  gemm_bt<64, 64, 2, 2, u16><<<dim3(128, 4), dim3(256), 0, stream>>>(t, xb, wvb, 256, 1024);
  // qkv = t @ Wu^T         M=8192 N=3072 K=256
  gemm_bt<128, 128, 4, 4, u16><<<dim3(64, 24), dim3(256), 0, stream>>>(qkv, t, wub, 3072, 256);
  // attention
  attn_kernel<<<dim3(16, 64), dim3(256), 0, stream>>>(yb, qkv);
  // z = y @ Wov^T          M=8192 N=256  K=1024
  gemm_bt<64, 64, 2, 2, u16><<<dim3(128, 4), dim3(256), 0, stream>>>(z, yb, wovb, 256, 1024);
  // out = z @ Wou^T        M=8192 N=1024 K=256  (fp32 out)
  gemm_bt<128, 128, 4, 4, float><<<dim3(64, 8), dim3(256), 0, stream>>>(out, z, woub, 1024, 256);
}

// Round 2
// 230.221 us; speedup vs baseline: 1.5898x; 1.5898x over previous
//
#include <hip/hip_runtime.h>
#include <hip/hip_bf16.h>

typedef __attribute__((ext_vector_type(8))) short short8;
typedef __attribute__((ext_vector_type(4))) float f32x4;
typedef __attribute__((ext_vector_type(16))) float f32x16;
typedef unsigned short u16;
typedef unsigned int u32;

__device__ __forceinline__ void gload_lds16(const void* g, void* l) {
  typedef const __attribute__((address_space(1))) u32 gu32;
  typedef __attribute__((address_space(3))) u32 lu32;
  __builtin_amdgcn_global_load_lds((gu32*)g, (lu32*)l, 16, 0, 0);
}

__device__ __forceinline__ u16 f2bf(float f) {
  union { float f; u32 u; } v; v.f = f;
  u32 u = v.u + 0x7FFFu + ((v.u >> 16) & 1u);
  return (u16)(u >> 16);
}

__device__ __forceinline__ u32 cvtpk(float lo, float hiv) {
  u32 r;
  asm("v_cvt_pk_bf16_f32 %0, %1, %2" : "=v"(r) : "v"(lo), "v"(hiv));
  return r;
}

__device__ __forceinline__ short8 lds_read8(const u16* base, int byteoff) {
  return *(const short8*)((const char*)base + byteoff);
}

// ---------------- fused fp32 -> bf16 cast of x + 4 weights ----------------
__global__ __launch_bounds__(256) void cast_all_kernel(
    const float* __restrict__ x, const float* __restrict__ wv,
    const float* __restrict__ wu, const float* __restrict__ wov,
    const float* __restrict__ wou, u16* __restrict__ dst) {
  const long N0 = 8388608, N1 = N0 + 262144, N2 = N1 + 786432,
             N3 = N2 + 262144, N4 = N3 + 262144;
  long i = (long)(blockIdx.x * 256 + threadIdx.x) * 8;
  if (i >= N4) return;
  const float* s;
  if (i < N0) s = x + i;
  else if (i < N1) s = wv + (i - N0);
  else if (i < N2) s = wu + (i - N1);
  else if (i < N3) s = wov + (i - N2);
  else s = wou + (i - N3);
  float4 a = *(const float4*)s;
  float4 b = *(const float4*)(s + 4);
  short8 o;
  o[0] = (short)f2bf(a.x); o[1] = (short)f2bf(a.y);
  o[2] = (short)f2bf(a.z); o[3] = (short)f2bf(a.w);
  o[4] = (short)f2bf(b.x); o[5] = (short)f2bf(b.y);
  o[6] = (short)f2bf(b.z); o[7] = (short)f2bf(b.w);
  *(short8*)(dst + i) = o;
}

// ---------------- C[M,N] = A[M,K] * B[N,K]^T, bf16 in, OutT out ----------------
template<int BM, int BN, int MR, int NR, typename OutT>
__global__ __launch_bounds__(256) void gemm_bt(
    OutT* __restrict__ C, const u16* __restrict__ A, const u16* __restrict__ B,
    int N, int K) {
  __shared__ u16 As[BM * 64];
  __shared__ u16 Bs[BN * 64];
  const int tid = threadIdx.x;
  const int l = tid & 63, w = tid >> 6;
  const int wr = w >> 1, wc = w & 1;
  const int bm = blockIdx.x * BM, bn = blockIdx.y * BN;
  const int srow = l >> 3, sslot = (l & 7) ^ srow;

  f32x4 acc[MR][NR] = {};

  const u16* Ag = A + (long)(bm + srow) * K + sslot * 8;
  const u16* Bg = B + (long)(bn + srow) * K + sslot * 8;
  constexpr int CA = BM / 32, CB = BN / 32;

  for (int kt = 0; kt < K; kt += 64) {
#pragma unroll
    for (int c = 0; c < CA; ++c) {
      int ch = w * CA + c;
      gload_lds16(Ag + (long)ch * 8 * K + kt, (char*)As + ch * 1024);
    }
#pragma unroll
    for (int c = 0; c < CB; ++c) {
      int ch = w * CB + c;
      gload_lds16(Bg + (long)ch * 8 * K + kt, (char*)Bs + ch * 1024);
    }
    __syncthreads();
    short8 af[MR][2], bf[NR][2];
#pragma unroll
    for (int i = 0; i < MR; ++i)
#pragma unroll
      for (int kk = 0; kk < 2; ++kk) {
        int row = wr * (MR * 16) + i * 16 + (l & 15);
        af[i][kk] = lds_read8(As, row * 128 + (((kk * 4 + (l >> 4)) ^ (l & 7)) * 16));
      }
#pragma unroll
    for (int j = 0; j < NR; ++j)
#pragma unroll
      for (int kk = 0; kk < 2; ++kk) {
        int col = wc * (NR * 16) + j * 16 + (l & 15);
        bf[j][kk] = lds_read8(Bs, col * 128 + (((kk * 4 + (l >> 4)) ^ (l & 7)) * 16));
      }
#pragma unroll
    for (int kk = 0; kk < 2; ++kk)
#pragma unroll
      for (int i = 0; i < MR; ++i)
#pragma unroll
        for (int j = 0; j < NR; ++j)
          acc[i][j] = __builtin_amdgcn_mfma_f32_16x16x32_bf16(
              af[i][kk], bf[j][kk], acc[i][j], 0, 0, 0);
    __syncthreads();
  }
#pragma unroll
  for (int i = 0; i < MR; ++i)
#pragma unroll
    for (int j = 0; j < NR; ++j) {
      int row = bm + wr * (MR * 16) + i * 16 + (l >> 4) * 4;
      int col = bn + wc * (NR * 16) + j * 16 + (l & 15);
#pragma unroll
      for (int r = 0; r < 4; ++r) {
        if constexpr (sizeof(OutT) == 4) {
          C[(long)(row + r) * N + col] = acc[i][j][r];
        } else {
          ((u16*)C)[(long)(row + r) * N + col] = f2bf(acc[i][j][r]);
        }
      }
    }
}

// ---------------- V transpose: Vt[b][h][d][t] from qkv v-part ----------------
// grid (T/64, B*H), 256 threads; 64t x 64d tile through LDS.
__global__ __launch_bounds__(256) void vtrans_kernel(
    u16* __restrict__ Vt, const u16* __restrict__ QKV) {
  constexpr int T = 2048, LDQ = 3072;
  __shared__ u16 L[64 * 80];   // [d][t], pitch 80 (16B-aligned rows, 8-bank shift)
  const int tid = threadIdx.x;
  const int t0 = blockIdx.x * 64, bh = blockIdx.y;
  const int b = bh >> 4, h = bh & 15;
  const u16* src = QKV + (long)b * T * LDQ + 2048 + h * 64;
#pragma unroll
  for (int it = 0; it < 2; ++it) {
    int row = (tid >> 3) + it * 32;      // t within tile
    int d0 = (tid & 7) * 8;
    short8 v = *(const short8*)(src + (long)(t0 + row) * LDQ + d0);
#pragma unroll
    for (int j = 0; j < 8; ++j)
      L[(d0 + j) * 80 + row] = (u16)(short)v[j];
  }
  __syncthreads();
  u16* dst = Vt + (long)bh * 64 * T + t0;
#pragma unroll
  for (int it = 0; it < 2; ++it) {
    int d = (tid >> 3) + it * 32;
    int c = (tid & 7) * 8;
    *(short8*)(dst + (long)d * T + c) = *(const short8*)(&L[d * 80 + c]);
  }
}

// ---------------- flash attention, swapped-operand 32x32 structure ----------------
// grid (T/128, B*H); 4 waves x 32 q-rows. KVBLK=64. S^T = mfma(K,Q); P stays in
// registers (cvt_pk + lane^32 exchange); O^T = mfma(V^T, P^T); epilogue transposes
// O^T through LDS for coalesced stores.
__global__ __launch_bounds__(256) void attn_kernel(
    u16* __restrict__ Y, const u16* __restrict__ QKV, const u16* __restrict__ Vt) {
  constexpr int T = 2048, LDQ = 3072;
  constexpr float SC = 0.18033688011112042f;  // (1/8) * log2(e)
  __shared__ u16 SMEM[8192];                  // Ks[4096] | Vs[4096]
  u16* Ks = SMEM;
  u16* Vs = SMEM + 4096;
  const int tid = threadIdx.x, l = tid & 63, w = tid >> 6;
  const int lq = l & 31, hi = l >> 5;
  const int qt = blockIdx.x, bh = blockIdx.y;
  const int b = bh >> 4, h = bh & 15;
  const long base = (long)b * T * LDQ;
  const int q0 = qt * 128 + w * 32;

  // Q as B-operand: qf[ks][j] = Q[q0+lq][ks*16 + hi*8 + j]
  short8 qf[4];
#pragma unroll
  for (int ks = 0; ks < 4; ++ks)
    qf[ks] = *(const short8*)(QKV + base + (long)(q0 + lq) * LDQ + h * 64 +
                              ks * 16 + hi * 8);

  f32x16 o0 = {}, o1 = {};              // O^T frags: d in [0,32), [32,64)
  float mrow = -3.0e38f, lrow = 0.0f;   // per-lane: own q-row = q0 + lq

  // staging geometry: chunk c -> row c>>3, phys slot c&7 holds logical slot ^ (row&7)
  const int c0 = w * 128, c1 = w * 128 + 64;
  const int kr0 = (c0 + l) >> 3, ds0 = ((c0 + l) & 7) ^ (kr0 & 7);
  const int kr1 = (c1 + l) >> 3, ds1 = ((c1 + l) & 7) ^ (kr1 & 7);
  const u16* Kg = QKV + base + 1024 + h * 64;
  const u16* Vg = Vt + (long)bh * 64 * T;

  for (int kt = 0; kt < T; kt += 64) {
    gload_lds16(Kg + (long)(kt + kr0) * LDQ + ds0 * 8, (char*)Ks + c0 * 16);
    gload_lds16(Kg + (long)(kt + kr1) * LDQ + ds1 * 8, (char*)Ks + c1 * 16);
    gload_lds16(Vg + (long)kr0 * T + kt + ds0 * 8, (char*)Vs + c0 * 16);
    gload_lds16(Vg + (long)kr1 * T + kt + ds1 * 8, (char*)Vs + c1 * 16);
    __syncthreads();

    // S^T[k, q] = sum_d K[k,d] Q[q,d]: A=K rows, B=Q cols
    f32x16 p0 = {}, p1 = {};
#pragma unroll
    for (int ks = 0; ks < 4; ++ks) {
      int psl = ((ks * 2 + hi) ^ (lq & 7)) * 16;
      short8 ka = lds_read8(Ks, lq * 128 + psl);
      short8 kb = lds_read8(Ks, (32 + lq) * 128 + psl);
      p0 = __builtin_amdgcn_mfma_f32_32x32x16_bf16(ka, qf[ks], p0, 0, 0, 0);
      p1 = __builtin_amdgcn_mfma_f32_32x32x16_bf16(kb, qf[ks], p1, 0, 0, 0);
    }

    // online softmax (lane owns q = q0+lq; k-halves split lane vs lane^32)
    float t[16];
#pragma unroll
    for (int r = 0; r < 16; ++r) t[r] = fmaxf(p0[r], p1[r]);
#pragma unroll
    for (int s = 8; s; s >>= 1)
#pragma unroll
      for (int r = 0; r < s; ++r) t[r] = fmaxf(t[r], t[r + s]);
    float mx = fmaxf(t[0], __shfl_xor(t[0], 32));
    float mnew = fmaxf(mrow, mx);
    float cr = exp2f((mrow - mnew) * SC);
    mrow = mnew;
    float msc = mnew * SC;
#pragma unroll
    for (int r = 0; r < 16; ++r) p0[r] = exp2f(fmaf(p0[r], SC, -msc));
#pragma unroll
    for (int r = 0; r < 16; ++r) p1[r] = exp2f(fmaf(p1[r], SC, -msc));
    float sum[16];
#pragma unroll
    for (int r = 0; r < 16; ++r) sum[r] = p0[r] + p1[r];
#pragma unroll
    for (int s = 8; s; s >>= 1)
#pragma unroll
      for (int r = 0; r < s; ++r) sum[r] += sum[r + s];
    float rs = sum[0] + __shfl_xor(sum[0], 32);
    lrow = lrow * cr + rs;
#pragma unroll
    for (int r = 0; r < 16; ++r) { o0[r] *= cr; o1[r] *= cr; }

    // P^T B-frags in-register + PV: O^T[d,q] += V^T[d,k] P^T[k,q]
#pragma unroll
    for (int ks = 0; ks < 4; ++ks) {
      const f32x16 ps = (ks < 2) ? p0 : p1;
      constexpr int R0[4] = {0, 8, 0, 8};
      const int r0 = R0[ks];
      u32 zl0 = cvtpk(ps[r0 + 0], ps[r0 + 1]);
      u32 zl2 = cvtpk(ps[r0 + 2], ps[r0 + 3]);
      u32 zh0 = cvtpk(ps[r0 + 4], ps[r0 + 5]);
      u32 zh2 = cvtpk(ps[r0 + 6], ps[r0 + 7]);
      u32 loc0 = hi ? zh0 : zl0, snd0 = hi ? zl0 : zh0;
      u32 loc2 = hi ? zh2 : zl2, snd2 = hi ? zl2 : zh2;
      u32 rcv0 = (u32)__shfl_xor((int)snd0, 32);
      u32 rcv2 = (u32)__shfl_xor((int)snd2, 32);
      union { u32 u[4]; short8 s; } pb;
      pb.u[0] = hi ? rcv0 : loc0;
      pb.u[1] = hi ? rcv2 : loc2;
      pb.u[2] = hi ? loc0 : rcv0;
      pb.u[3] = hi ? loc2 : rcv2;
      int psl = ((ks * 2 + hi) ^ (lq & 7)) * 16;
      short8 va = lds_read8(Vs, lq * 128 + psl);
      short8 vb = lds_read8(Vs, (32 + lq) * 128 + psl);
      o0 = __builtin_amdgcn_mfma_f32_32x32x16_bf16(va, pb.s, o0, 0, 0, 0);
      o1 = __builtin_amdgcn_mfma_f32_32x32x16_bf16(vb, pb.s, o1, 0, 0, 0);
    }
    __syncthreads();
  }

  // epilogue: O^T -> LDS (swizzled) -> coalesced row-major store
  float inv = 1.0f / lrow;
  const int row = w * 32 + lq;
#pragma unroll
  for (int df = 0; df < 2; ++df)
#pragma unroll
    for (int r = 0; r < 16; ++r) {
      int d = df * 32 + (r & 3) + 8 * (r >> 2) + 4 * hi;
      float v = (df ? o1[r] : o0[r]) * inv;
      *(u16*)((char*)SMEM + row * 128 + (((d >> 3) ^ (row & 7)) * 16) + (d & 7) * 2) =
          f2bf(v);
    }
  __syncthreads();
#pragma unroll
  for (int it = 0; it < 4; ++it) {
    int c = tid + it * 256;      // 1024 chunks: q 0..127 x 8 d-slots
    int q = c >> 3, g = c & 7;
    int pg = g ^ (q & 7);
    short8 vv = *(const short8*)((const char*)SMEM + q * 128 + pg * 16);
    *(short8*)(Y + (long)(b * T + qt * 128 + q) * 1024 + h * 64 + g * 8) = vv;
  }
}

__global__ void ws_too_small_kernel(float* out) { out[0] = 3.0e38f; }

// ---------------- launch ----------------
extern "C" void kernel_launch(void* const* d_in, const int* in_sizes, int n_in,
                              void* d_out, int out_size, void* d_ws, size_t ws_size,
                              hipStream_t stream) {
  (void)in_sizes; (void)n_in; (void)out_size;
  const float* x   = (const float*)d_in[0];
  const float* wv  = (const float*)d_in[1];
  const float* wu  = (const float*)d_in[2];
  const float* wov = (const float*)d_in[3];
  const float* wou = (const float*)d_in[4];
  float* out = (float*)d_out;
  u16* ws = (u16*)d_ws;

  // bf16 workspace layout (element offsets)
  u16* xb   = ws;                // x        [8192,1024]  (dead after gemm1 -> reused as Vt)
  u16* wvb  = ws + 8388608;      // W_qkv_v  [256,1024]
  u16* wub  = ws + 8650752;      // W_qkv_u  [3072,256]
  u16* wovb = ws + 9437184;      // W_o_v    [256,1024]
  u16* woub = ws + 9699328;      // W_o_u    [1024,256]
  u16* t    = ws + 9961472;      // x@Wv^T   [8192,256]
  u16* qkv  = ws + 12058624;     // [8192,3072]
  u16* yb   = ws + 37224448;     // attn out [8192,1024]
  u16* z    = ws + 45613056;     // y@Wov^T  [8192,256]
  u16* vt   = xb;                // Vt [B,H,64,2048] = 8388608 elems, exact overlay

  if (ws_size < 95420416ull) {   // distinctive failure marker
    ws_too_small_kernel<<<1, 1, 0, stream>>>(out);
    return;
  }

  cast_all_kernel<<<dim3(4864), dim3(256), 0, stream>>>(x, wv, wu, wov, wou, ws);
  // t = x @ Wv^T           M=8192 N=256  K=1024
  gemm_bt<64, 64, 2, 2, u16><<<dim3(128, 4), dim3(256), 0, stream>>>(t, xb, wvb, 256, 1024);
  // qkv = t @ Wu^T         M=8192 N=3072 K=256
  gemm_bt<128, 128, 4, 4, u16><<<dim3(64, 24), dim3(256), 0, stream>>>(qkv, t, wub, 3072, 256);
  // Vt = transpose of V part (overlays dead xb)
  vtrans_kernel<<<dim3(32, 64), dim3(256), 0, stream>>>(vt, qkv);
  // attention
  attn_kernel<<<dim3(16, 64), dim3(256), 0, stream>>>(yb, qkv, vt);
  // z = y @ Wov^T          M=8192 N=256  K=1024
  gemm_bt<64, 64, 2, 2, u16><<<dim3(128, 4), dim3(256), 0, stream>>>(z, yb, wovb, 256, 1024);
  // out = z @ Wou^T        M=8192 N=1024 K=256  (fp32 out)
  gemm_bt<128, 128, 4, 4, float><<<dim3(64, 8), dim3(256), 0, stream>>>(out, z, woub, 1024, 256);
}

// Round 3
// 180.457 us; speedup vs baseline: 2.0282x; 1.2758x over previous
//
#include <hip/hip_runtime.h>
#include <hip/hip_bf16.h>

typedef __attribute__((ext_vector_type(8))) short short8;
typedef __attribute__((ext_vector_type(4))) float f32x4;
typedef __attribute__((ext_vector_type(8))) float f32x8;
typedef __attribute__((ext_vector_type(16))) float f32x16;
typedef unsigned short u16;
typedef unsigned int u32;

__device__ __forceinline__ void gload_lds16(const void* g, void* l) {
  typedef const __attribute__((address_space(1))) u32 gu32;
  typedef __attribute__((address_space(3))) u32 lu32;
  __builtin_amdgcn_global_load_lds((gu32*)g, (lu32*)l, 16, 0, 0);
}

__device__ __forceinline__ u16 f2bf(float f) {
  union { float f; u32 u; } v; v.f = f;
  u32 u = v.u + 0x7FFFu + ((v.u >> 16) & 1u);
  return (u16)(u >> 16);
}

__device__ __forceinline__ u32 cvtpk(float lo, float hiv) {
  u32 r;
  asm("v_cvt_pk_bf16_f32 %0, %1, %2" : "=v"(r) : "v"(lo), "v"(hiv));
  return r;
}

__device__ __forceinline__ void plswap(u32& a, u32& b) {
  asm("v_permlane32_swap_b32 %0, %1" : "+v"(a), "+v"(b));
}

__device__ __forceinline__ float fexp2(float x) {
#if __has_builtin(__builtin_amdgcn_exp2f)
  return __builtin_amdgcn_exp2f(x);
#else
  return exp2f(x);
#endif
}

__device__ __forceinline__ short8 lds_read8(const u16* base, int byteoff) {
  return *(const short8*)((const char*)base + byteoff);
}

// ---------------- fused fp32 -> bf16 cast of x + 4 weights ----------------
__global__ __launch_bounds__(256) void cast_all_kernel(
    const float* __restrict__ x, const float* __restrict__ wv,
    const float* __restrict__ wu, const float* __restrict__ wov,
    const float* __restrict__ wou, u16* __restrict__ dst) {
  const long N0 = 8388608, N1 = N0 + 262144, N2 = N1 + 786432,
             N3 = N2 + 262144, N4 = N3 + 262144;
  long i = (long)(blockIdx.x * 256 + threadIdx.x) * 8;
  if (i >= N4) return;
  const float* s;
  if (i < N0) s = x + i;
  else if (i < N1) s = wv + (i - N0);
  else if (i < N2) s = wu + (i - N1);
  else if (i < N3) s = wov + (i - N2);
  else s = wou + (i - N3);
  float4 a = *(const float4*)s;
  float4 b = *(const float4*)(s + 4);
  short8 o;
  o[0] = (short)f2bf(a.x); o[1] = (short)f2bf(a.y);
  o[2] = (short)f2bf(a.z); o[3] = (short)f2bf(a.w);
  o[4] = (short)f2bf(b.x); o[5] = (short)f2bf(b.y);
  o[6] = (short)f2bf(b.z); o[7] = (short)f2bf(b.w);
  *(short8*)(dst + i) = o;
}

// ---------------- C[M,N] = A[M,K] * B[N,K]^T, bf16 in, OutT out ----------------
template<int BM, int BN, int MR, int NR, typename OutT>
__global__ __launch_bounds__(256) void gemm_bt(
    OutT* __restrict__ C, const u16* __restrict__ A, const u16* __restrict__ B,
    int N, int K) {
  __shared__ u16 As[BM * 64];
  __shared__ u16 Bs[BN * 64];
  const int tid = threadIdx.x;
  const int l = tid & 63, w = tid >> 6;
  const int wr = w >> 1, wc = w & 1;
  const int bm = blockIdx.x * BM, bn = blockIdx.y * BN;
  const int srow = l >> 3, sslot = (l & 7) ^ srow;

  f32x4 acc[MR][NR] = {};

  const u16* Ag = A + (long)(bm + srow) * K + sslot * 8;
  const u16* Bg = B + (long)(bn + srow) * K + sslot * 8;
  constexpr int CA = BM / 32, CB = BN / 32;

  for (int kt = 0; kt < K; kt += 64) {
#pragma unroll
    for (int c = 0; c < CA; ++c) {
      int ch = w * CA + c;
      gload_lds16(Ag + (long)ch * 8 * K + kt, (char*)As + ch * 1024);
    }
#pragma unroll
    for (int c = 0; c < CB; ++c) {
      int ch = w * CB + c;
      gload_lds16(Bg + (long)ch * 8 * K + kt, (char*)Bs + ch * 1024);
    }
    __syncthreads();
    short8 af[MR][2], bf[NR][2];
#pragma unroll
    for (int i = 0; i < MR; ++i)
#pragma unroll
      for (int kk = 0; kk < 2; ++kk) {
        int row = wr * (MR * 16) + i * 16 + (l & 15);
        af[i][kk] = lds_read8(As, row * 128 + (((kk * 4 + (l >> 4)) ^ (l & 7)) * 16));
      }
#pragma unroll
    for (int j = 0; j < NR; ++j)
#pragma unroll
      for (int kk = 0; kk < 2; ++kk) {
        int col = wc * (NR * 16) + j * 16 + (l & 15);
        bf[j][kk] = lds_read8(Bs, col * 128 + (((kk * 4 + (l >> 4)) ^ (l & 7)) * 16));
      }
#pragma unroll
    for (int kk = 0; kk < 2; ++kk)
#pragma unroll
      for (int i = 0; i < MR; ++i)
#pragma unroll
        for (int j = 0; j < NR; ++j)
          acc[i][j] = __builtin_amdgcn_mfma_f32_16x16x32_bf16(
              af[i][kk], bf[j][kk], acc[i][j], 0, 0, 0);
    __syncthreads();
  }
#pragma unroll
  for (int i = 0; i < MR; ++i)
#pragma unroll
    for (int j = 0; j < NR; ++j) {
      int row = bm + wr * (MR * 16) + i * 16 + (l >> 4) * 4;
      int col = bn + wc * (NR * 16) + j * 16 + (l & 15);
#pragma unroll
      for (int r = 0; r < 4; ++r) {
        if constexpr (sizeof(OutT) == 4) {
          C[(long)(row + r) * N + col] = acc[i][j][r];
        } else {
          ((u16*)C)[(long)(row + r) * N + col] = f2bf(acc[i][j][r]);
        }
      }
    }
}

// ---------------- V transpose: Vt[b][h][d][t] from qkv v-part ----------------
__global__ __launch_bounds__(256) void vtrans_kernel(
    u16* __restrict__ Vt, const u16* __restrict__ QKV) {
  constexpr int T = 2048, LDQ = 3072;
  __shared__ u16 L[64 * 80];
  const int tid = threadIdx.x;
  const int t0 = blockIdx.x * 64, bh = blockIdx.y;
  const int b = bh >> 4, h = bh & 15;
  const u16* src = QKV + (long)b * T * LDQ + 2048 + h * 64;
#pragma unroll
  for (int it = 0; it < 2; ++it) {
    int row = (tid >> 3) + it * 32;
    int d0 = (tid & 7) * 8;
    short8 v = *(const short8*)(src + (long)(t0 + row) * LDQ + d0);
#pragma unroll
    for (int j = 0; j < 8; ++j)
      L[(d0 + j) * 80 + row] = (u16)(short)v[j];
  }
  __syncthreads();
  u16* dst = Vt + (long)bh * 64 * T + t0;
#pragma unroll
  for (int it = 0; it < 2; ++it) {
    int d = (tid >> 3) + it * 32;
    int c = (tid & 7) * 8;
    *(short8*)(dst + (long)d * T + c) = *(const short8*)(&L[d * 80 + c]);
  }
}

// ---------------- flash attention, swapped-operand 32x32, VALU-lean ----------------
// grid (T/128, B*H); 4 waves x 32 q-rows; KVBLK=64; double-buffered staging.
__global__ __launch_bounds__(256, 4) void attn_kernel(
    u16* __restrict__ Y, const u16* __restrict__ QKV, const u16* __restrict__ Vt) {
  constexpr int T = 2048, LDQ = 3072;
  constexpr float SC = 0.18033688011112042f;  // (1/8) * log2(e)
  __shared__ u16 SMEM[16384];                 // 2 x (Ks 8KB | Vs 8KB)
  const int tid = threadIdx.x, l = tid & 63, w = tid >> 6;
  const int lq = l & 31, hi = l >> 5;
  const int qt = blockIdx.x, bh = blockIdx.y;
  const int b = bh >> 4, h = bh & 15;
  const long base = (long)b * T * LDQ;
  const int q0 = qt * 128 + w * 32;

  short8 qf[4];
#pragma unroll
  for (int ks = 0; ks < 4; ++ks)
    qf[ks] = *(const short8*)(QKV + base + (long)(q0 + lq) * LDQ + h * 64 +
                              ks * 16 + hi * 8);

  f32x16 o0 = {}, o1 = {};
  float mrow = -3.0e38f, lrow = 0.0f;

  const int c0 = w * 128, c1 = w * 128 + 64;
  const int kr0 = (c0 + l) >> 3, ds0 = ((c0 + l) & 7) ^ (kr0 & 7);
  const int kr1 = (c1 + l) >> 3, ds1 = ((c1 + l) & 7) ^ (kr1 & 7);
  const u16* Kg = QKV + base + 1024 + h * 64;
  const u16* Vg = Vt + (long)bh * 64 * T;

  auto STAGE = [&](int kt, int s) {
    u16* Kd = SMEM + s * 8192;
    u16* Vd = Kd + 4096;
    gload_lds16(Kg + (long)(kt + kr0) * LDQ + ds0 * 8, (char*)Kd + c0 * 16);
    gload_lds16(Kg + (long)(kt + kr1) * LDQ + ds1 * 8, (char*)Kd + c1 * 16);
    gload_lds16(Vg + (long)kr0 * T + kt + ds0 * 8, (char*)Vd + c0 * 16);
    gload_lds16(Vg + (long)kr1 * T + kt + ds1 * 8, (char*)Vd + c1 * 16);
  };

  const int pslA[4] = {((0 + hi) ^ (lq & 7)) * 16, ((2 + hi) ^ (lq & 7)) * 16,
                       ((4 + hi) ^ (lq & 7)) * 16, ((6 + hi) ^ (lq & 7)) * 16};

  auto COMPUTE = [&](const u16* Ks, const u16* Vs) {
    // S^T = K * Q^T (A = K rows from LDS, B = Q cols in regs)
    f32x16 p0 = {}, p1 = {};
#pragma unroll
    for (int ks = 0; ks < 4; ++ks) {
      short8 ka = lds_read8(Ks, lq * 128 + pslA[ks]);
      short8 kb = lds_read8(Ks, (32 + lq) * 128 + pslA[ks]);
      p0 = __builtin_amdgcn_mfma_f32_32x32x16_bf16(ka, qf[ks], p0, 0, 0, 0);
      p1 = __builtin_amdgcn_mfma_f32_32x32x16_bf16(kb, qf[ks], p1, 0, 0, 0);
    }
    // row max (vector tree -> pk_max), cross-half via shfl
    f32x16 mv = __builtin_elementwise_max(p0, p1);
    f32x8 m8 = __builtin_elementwise_max(
        __builtin_shufflevector(mv, mv, 0, 1, 2, 3, 4, 5, 6, 7),
        __builtin_shufflevector(mv, mv, 8, 9, 10, 11, 12, 13, 14, 15));
    f32x4 m4 = __builtin_elementwise_max(
        __builtin_shufflevector(m8, m8, 0, 1, 2, 3),
        __builtin_shufflevector(m8, m8, 4, 5, 6, 7));
    float mx = fmaxf(fmaxf(m4[0], m4[1]), fmaxf(m4[2], m4[3]));
    mx = fmaxf(mx, __shfl_xor(mx, 32));
    // defer-max: only rescale when the raw max grows by > 40 (P <= 2^7.3)
    if (!__all(mx - mrow <= 40.0f)) {
      float mnew = fmaxf(mrow, mx);
      float cr = fexp2((mrow - mnew) * SC);
      mrow = mnew;
      lrow *= cr;
      o0 *= cr;
      o1 *= cr;
    }
    float msc = mrow * SC;
    p0 = p0 * SC - msc;   // v_pk_fma_f32
    p1 = p1 * SC - msc;
#pragma unroll
    for (int r = 0; r < 16; ++r) p0[r] = fexp2(p0[r]);
#pragma unroll
    for (int r = 0; r < 16; ++r) p1[r] = fexp2(p1[r]);
    // row sum (vector tree -> pk_add)
    f32x16 sv = p0 + p1;
    f32x8 s8 = __builtin_shufflevector(sv, sv, 0, 1, 2, 3, 4, 5, 6, 7) +
               __builtin_shufflevector(sv, sv, 8, 9, 10, 11, 12, 13, 14, 15);
    f32x4 s4 = __builtin_shufflevector(s8, s8, 0, 1, 2, 3) +
               __builtin_shufflevector(s8, s8, 4, 5, 6, 7);
    float rs = (s4[0] + s4[1]) + (s4[2] + s4[3]);
    rs += __shfl_xor(rs, 32);
    lrow += rs;
    // P -> bf16 B-frags via cvt_pk + permlane32_swap (no selects), then PV
#pragma unroll
    for (int ks = 0; ks < 4; ++ks) {
      const f32x16& ps = (ks < 2) ? p0 : p1;
      const int r0 = (ks & 1) * 8;
      u32 uA = cvtpk(ps[r0 + 0], ps[r0 + 1]);
      u32 uB = cvtpk(ps[r0 + 2], ps[r0 + 3]);
      u32 uC = cvtpk(ps[r0 + 4], ps[r0 + 5]);
      u32 uD = cvtpk(ps[r0 + 6], ps[r0 + 7]);
      plswap(uA, uC);
      plswap(uB, uD);
      union { u32 u[4]; short8 s; } pb;
      pb.u[0] = uA; pb.u[1] = uB; pb.u[2] = uC; pb.u[3] = uD;
      short8 va = lds_read8(Vs, lq * 128 + pslA[ks]);
      short8 vb = lds_read8(Vs, (32 + lq) * 128 + pslA[ks]);
      o0 = __builtin_amdgcn_mfma_f32_32x32x16_bf16(va, pb.s, o0, 0, 0, 0);
      o1 = __builtin_amdgcn_mfma_f32_32x32x16_bf16(vb, pb.s, o1, 0, 0, 0);
    }
  };

  STAGE(0, 0);
  __syncthreads();
  for (int t = 0; t < T / 64; ++t) {
    if (t + 1 < T / 64) STAGE((t + 1) * 64, (t + 1) & 1);
    const u16* Ks = SMEM + (t & 1) * 8192;
    COMPUTE(Ks, Ks + 4096);
    __syncthreads();
  }

  // epilogue: O^T -> LDS (swizzled) -> coalesced row-major store
  float inv = 1.0f / lrow;
  const int row = w * 32 + lq;
#pragma unroll
  for (int df = 0; df < 2; ++df)
#pragma unroll
    for (int r = 0; r < 16; ++r) {
      int d = df * 32 + (r & 3) + 8 * (r >> 2) + 4 * hi;
      float v = (df ? o1[r] : o0[r]) * inv;
      *(u16*)((char*)SMEM + row * 128 + (((d >> 3) ^ (row & 7)) * 16) + (d & 7) * 2) =
          f2bf(v);
    }
  __syncthreads();
#pragma unroll
  for (int it = 0; it < 4; ++it) {
    int c = tid + it * 256;
    int q = c >> 3, g = c & 7;
    int pg = g ^ (q & 7);
    short8 vv = *(const short8*)((const char*)SMEM + q * 128 + pg * 16);
    *(short8*)(Y + (long)(b * T + qt * 128 + q) * 1024 + h * 64 + g * 8) = vv;
  }
}

__global__ void ws_too_small_kernel(float* out) { out[0] = 3.0e38f; }

// ---------------- launch ----------------
extern "C" void kernel_launch(void* const* d_in, const int* in_sizes, int n_in,
                              void* d_out, int out_size, void* d_ws, size_t ws_size,
                              hipStream_t stream) {
  (void)in_sizes; (void)n_in; (void)out_size;
  const float* x   = (const float*)d_in[0];
  const float* wv  = (const float*)d_in[1];
  const float* wu  = (const float*)d_in[2];
  const float* wov = (const float*)d_in[3];
  const float* wou = (const float*)d_in[4];
  float* out = (float*)d_out;
  u16* ws = (u16*)d_ws;

  u16* xb   = ws;                // x        [8192,1024]  (dead after gemm1 -> Vt)
  u16* wvb  = ws + 8388608;      // W_qkv_v  [256,1024]
  u16* wub  = ws + 8650752;      // W_qkv_u  [3072,256]
  u16* wovb = ws + 9437184;      // W_o_v    [256,1024]
  u16* woub = ws + 9699328;      // W_o_u    [1024,256]
  u16* t    = ws + 9961472;      // x@Wv^T   [8192,256]
  u16* qkv  = ws + 12058624;     // [8192,3072]
  u16* yb   = ws + 37224448;     // attn out [8192,1024]
  u16* z    = ws + 45613056;     // y@Wov^T  [8192,256]
  u16* vt   = xb;                // Vt [B,H,64,2048]

  if (ws_size < 95420416ull) {
    ws_too_small_kernel<<<1, 1, 0, stream>>>(out);
    return;
  }

  cast_all_kernel<<<dim3(4864), dim3(256), 0, stream>>>(x, wv, wu, wov, wou, ws);
  gemm_bt<64, 64, 2, 2, u16><<<dim3(128, 4), dim3(256), 0, stream>>>(t, xb, wvb, 256, 1024);
  gemm_bt<128, 128, 4, 4, u16><<<dim3(64, 24), dim3(256), 0, stream>>>(qkv, t, wub, 3072, 256);
  vtrans_kernel<<<dim3(32, 64), dim3(256), 0, stream>>>(vt, qkv);
  attn_kernel<<<dim3(16, 64), dim3(256), 0, stream>>>(yb, qkv, vt);
  gemm_bt<64, 64, 2, 2, u16><<<dim3(128, 4), dim3(256), 0, stream>>>(z, yb, wovb, 256, 1024);
  gemm_bt<128, 128, 4, 4, float><<<dim3(64, 8), dim3(256), 0, stream>>>(out, z, woub, 1024, 256);
}